// Round 10
// baseline (624.449 us; speedup 1.0000x reference)
//
#include <hip/hip_runtime.h>
#include <math.h>

#define B_ 32
#define SSRC 512
#define D_ 512
#define STRIDE_ 4
#define V_ 512
#define L_ 256
#define T_ (SSRC * STRIDE_)   // 2048
#define S_ (2 * L_ + 1)       // 513
#define BLANKI 1
#define PSTRIDE 264           // compact prob row stride (ushorts)
#define BOOST 4096.0f         // 2^12 pre-boost on gathered probs
#define BOOST_BITS 12

typedef __attribute__((ext_vector_type(8))) short bf16x8;
typedef __attribute__((ext_vector_type(4))) float f32x4;

__device__ __forceinline__ unsigned short bf16r(float x) {
    unsigned u = __float_as_uint(x);
    return (unsigned short)((u + 0x7fffu + ((u >> 16) & 1u)) >> 16);
}
__device__ __forceinline__ float bf2f(unsigned short u) {
    return __uint_as_float((unsigned)u << 16);
}
__device__ __forceinline__ void gl_lds16(const unsigned short* g, unsigned short* l) {
    __builtin_amdgcn_global_load_lds(
        (const __attribute__((address_space(1))) unsigned int*)g,
        (__attribute__((address_space(3))) unsigned int*)l, 16, 0, 0);
}

// ---------------------------------------------------------------------------
__global__ __launch_bounds__(256) void combine_bias(
    const float* __restrict__ b_exp, const float* __restrict__ W1,
    const float* __restrict__ b1, float* __restrict__ bc)
{
    int j = blockIdx.x * 256 + threadIdx.x;
    int k = j >> 10, h = j & 1023;
    float s = b1[h];
    const float* be = b_exp + k * 512;
    for (int d = 0; d < 512; ++d)
        s = fmaf(be[d], W1[d * 1024 + h], s);
    bc[j] = s;
}

// ---------------------------------------------------------------------------
__global__ __launch_bounds__(256) void transpose_cvt(
    const float* __restrict__ in, unsigned short* __restrict__ out, int R, int C)
{
    __shared__ float tile[32][33];
    int bx = blockIdx.x * 32, by = blockIdx.y * 32;
    int tx = threadIdx.x, ty = threadIdx.y;
#pragma unroll
    for (int i = 0; i < 32; i += 8)
        tile[ty + i][tx] = in[(size_t)(by + ty + i) * C + bx + tx];
    __syncthreads();
#pragma unroll
    for (int i = 0; i < 32; i += 8)
        out[(size_t)(bx + ty + i) * R + by + tx] = bf16r(tile[tx][ty + i]);
}

__global__ __launch_bounds__(256) void cvt_f32_bf16(
    const float* __restrict__ in, unsigned short* __restrict__ out, int n4)
{
    int i = blockIdx.x * 256 + threadIdx.x;
    if (i >= n4) return;
    float4 v = ((const float4*)in)[i];
    ushort4 o;
    o.x = bf16r(v.x); o.y = bf16r(v.y); o.z = bf16r(v.z); o.w = bf16r(v.w);
    ((ushort4*)out)[i] = o;
}

// ---------------------------------------------------------------------------
// bf16 MFMA GEMM (m97 structure) + bijective XCD swizzle (nwg % 8 == 0).
// Optional gridDim.z slicing via element offsets zA/zBT/zC.
// ---------------------------------------------------------------------------
template <bool RELU, bool OUTBF16, bool BIAS>
__global__ __launch_bounds__(256) void gemm_mfma(
    const unsigned short* __restrict__ A, int lda, long zA,
    const unsigned short* __restrict__ BT, int ldb, long zBT,
    void* __restrict__ Cvoid, int ldc, long zC,
    const float* __restrict__ bias, int K)
{
    __shared__ unsigned short As[2][128][32];
    __shared__ unsigned short Bs[2][128][32];
    const int tid = threadIdx.x;
    const int wid = tid >> 6, lane = tid & 63;

    A  += (size_t)blockIdx.z * zA;
    BT += (size_t)blockIdx.z * zBT;
    unsigned short* Cb = OUTBF16 ? ((unsigned short*)Cvoid + (size_t)blockIdx.z * zC) : nullptr;
    float*          Cf = OUTBF16 ? nullptr : ((float*)Cvoid + (size_t)blockIdx.z * zC);

    const int gx = gridDim.x;
    int wg = blockIdx.y * gx + blockIdx.x;
    const int q = (gx * gridDim.y) >> 3;
    wg = (wg & 7) * q + (wg >> 3);
    const int bm = (wg / gx) * 128, bn = (wg % gx) * 128;

    const int wm = (wid >> 1) * 64, wn = (wid & 1) * 64;

    f32x4 acc[4][4] = {};
    const int r_in = lane >> 2;
    const int cch = (lane & 3) * 8;
    const int rbase = wid * 32;

    auto stage = [&](int buf, int k0) {
#pragma unroll
        for (int i = 0; i < 2; ++i) {
            int rloc = rbase + i * 16;
            gl_lds16(A  + (size_t)(bm + rloc + r_in) * lda + k0 + cch, &As[buf][rloc][0]);
            gl_lds16(BT + (size_t)(bn + rloc + r_in) * ldb + k0 + cch, &Bs[buf][rloc][0]);
        }
    };

    const int nt = K / 32;
    stage(0, 0);
    for (int t = 0; t < nt; ++t) {
        int cur = t & 1;
        __syncthreads();
        if (t + 1 < nt) stage(cur ^ 1, (t + 1) * 32);
        bf16x8 af[4], bfr[4];
#pragma unroll
        for (int mi = 0; mi < 4; ++mi)
            af[mi] = *(const bf16x8*)&As[cur][wm + mi * 16 + (lane & 15)][(lane >> 4) * 8];
#pragma unroll
        for (int ni = 0; ni < 4; ++ni)
            bfr[ni] = *(const bf16x8*)&Bs[cur][wn + ni * 16 + (lane & 15)][(lane >> 4) * 8];
#pragma unroll
        for (int mi = 0; mi < 4; ++mi)
#pragma unroll
            for (int ni = 0; ni < 4; ++ni)
                acc[mi][ni] = __builtin_amdgcn_mfma_f32_16x16x32_bf16(
                    af[mi], bfr[ni], acc[mi][ni], 0, 0, 0);
    }

#pragma unroll
    for (int ni = 0; ni < 4; ++ni) {
        int gcol = bn + wn + ni * 16 + (lane & 15);
        float bv = BIAS ? bias[gcol] : 0.f;
#pragma unroll
        for (int mi = 0; mi < 4; ++mi) {
#pragma unroll
            for (int q2 = 0; q2 < 4; ++q2) {
                int grow = bm + wm + mi * 16 + ((lane >> 4) << 2) + q2;
                float x = acc[mi][ni][q2] + bv;
                if (RELU) x = fmaxf(x, 0.f);
                if (OUTBF16)
                    Cb[(size_t)grow * ldc + gcol] = bf16r(x);
                else
                    Cf[(size_t)grow * ldc + gcol] = x;
            }
        }
    }
}

// ---------------------------------------------------------------------------
// Fused GEMM2 + log_softmax + prob gather. One block = 64 logits rows x V=512
// (full row => softmax is block-local). A = H [65536][1024] bf16 living in
// d_out; output logprobs f32 written IN-PLACE over the same rows (row w of H
// occupies the same bytes as row w of logprobs; each block consumes its own
// rows in the K-loop before overwriting them; no other block touches them).
// 256 thr = 4 waves, wave wv owns cols [wv*128, wv*128+128), 4x8 MFMA frags.
// ---------------------------------------------------------------------------
__global__ __launch_bounds__(256) void gemm2_lsm(
    const unsigned short* __restrict__ H,     // [65536][1024] bf16 (= d_out)
    const unsigned short* __restrict__ W2T,   // [512][1024] bf16
    const float* __restrict__ b2,             // [512]
    const int* __restrict__ targets,          // [B][256]
    float* __restrict__ lp,                   // [65536][512] f32 (= d_out)
    unsigned short* __restrict__ P)           // [65536][PSTRIDE]
{
    __shared__ unsigned short SH[36864];      // 72 KB: staging, then probs
    __shared__ float redm[4][64], reds[4][64];
    __shared__ int s_tg[256];

    const int tid = threadIdx.x;
    const int wv = tid >> 6, lane = tid & 63;
    const int r0 = blockIdx.x * 64;           // first row
    const int b = r0 >> 11;                   // batch index (2048 rows/batch)

    s_tg[tid] = targets[b * L_ + tid];

    // staging: A(64x32) = issues 0..3, B(512x32) = issues 4..35; 9 per wave.
    auto stage = [&](int buf, int k0) {
#pragma unroll
        for (int ii = 0; ii < 9; ++ii) {
            int issue = wv * 9 + ii;
            if (issue < 4) {
                int rr = issue * 16;
                gl_lds16(H + (size_t)(r0 + rr + (lane >> 2)) * 1024 + k0 + (lane & 3) * 8,
                         &SH[buf * 2048 + rr * 32]);
            } else {
                int rr = (issue - 4) * 16;
                gl_lds16(W2T + (size_t)(rr + (lane >> 2)) * 1024 + k0 + (lane & 3) * 8,
                         &SH[4096 + buf * 16384 + rr * 32]);
            }
        }
    };

    f32x4 acc[4][8] = {};
    stage(0, 0);
    for (int t = 0; t < 32; ++t) {
        int cur = t & 1;
        __syncthreads();
        if (t + 1 < 32) stage(cur ^ 1, (t + 1) * 32);
        bf16x8 af[4], bfm[8];
#pragma unroll
        for (int mi = 0; mi < 4; ++mi)
            af[mi] = *(const bf16x8*)&SH[cur * 2048 + (mi * 16 + (lane & 15)) * 32 + (lane >> 4) * 8];
#pragma unroll
        for (int ni = 0; ni < 8; ++ni)
            bfm[ni] = *(const bf16x8*)&SH[4096 + cur * 16384 +
                                          (wv * 128 + ni * 16 + (lane & 15)) * 32 + (lane >> 4) * 8];
#pragma unroll
        for (int mi = 0; mi < 4; ++mi)
#pragma unroll
            for (int ni = 0; ni < 8; ++ni)
                acc[mi][ni] = __builtin_amdgcn_mfma_f32_16x16x32_bf16(
                    af[mi], bfm[ni], acc[mi][ni], 0, 0, 0);
    }

    // ---- epilogue: bias, row softmax (cross-wave), write lp + probs ----
    float bcol[8];
#pragma unroll
    for (int ni = 0; ni < 8; ++ni) bcol[ni] = b2[wv * 128 + ni * 16 + (lane & 15)];
#pragma unroll
    for (int mi = 0; mi < 4; ++mi)
#pragma unroll
        for (int ni = 0; ni < 8; ++ni)
#pragma unroll
            for (int q = 0; q < 4; ++q) acc[mi][ni][q] += bcol[ni];

    // per-row max: lane-local over ni, butterfly over the 16-lane col group
    float rm[4][4];
#pragma unroll
    for (int mi = 0; mi < 4; ++mi)
#pragma unroll
        for (int q = 0; q < 4; ++q) {
            float m = acc[mi][0][q];
#pragma unroll
            for (int ni = 1; ni < 8; ++ni) m = fmaxf(m, acc[mi][ni][q]);
            rm[mi][q] = m;
        }
#pragma unroll
    for (int off = 1; off < 16; off <<= 1)
#pragma unroll
        for (int mi = 0; mi < 4; ++mi)
#pragma unroll
            for (int q = 0; q < 4; ++q)
                rm[mi][q] = fmaxf(rm[mi][q], __shfl_xor(rm[mi][q], off));
    if ((lane & 15) == 0) {
#pragma unroll
        for (int mi = 0; mi < 4; ++mi)
#pragma unroll
            for (int q = 0; q < 4; ++q)
                redm[wv][mi * 16 + ((lane >> 4) << 2) + q] = rm[mi][q];
    }
    __syncthreads();
#pragma unroll
    for (int mi = 0; mi < 4; ++mi)
#pragma unroll
        for (int q = 0; q < 4; ++q) {
            int row = mi * 16 + ((lane >> 4) << 2) + q;
            rm[mi][q] = fmaxf(fmaxf(redm[0][row], redm[1][row]),
                              fmaxf(redm[2][row], redm[3][row]));
        }
    // per-row sum of exp
    float rs[4][4];
#pragma unroll
    for (int mi = 0; mi < 4; ++mi)
#pragma unroll
        for (int q = 0; q < 4; ++q) {
            float s = 0.f;
#pragma unroll
            for (int ni = 0; ni < 8; ++ni) s += expf(acc[mi][ni][q] - rm[mi][q]);
            rs[mi][q] = s;
        }
#pragma unroll
    for (int off = 1; off < 16; off <<= 1)
#pragma unroll
        for (int mi = 0; mi < 4; ++mi)
#pragma unroll
            for (int q = 0; q < 4; ++q)
                rs[mi][q] += __shfl_xor(rs[mi][q], off);
    if ((lane & 15) == 0) {
#pragma unroll
        for (int mi = 0; mi < 4; ++mi)
#pragma unroll
            for (int q = 0; q < 4; ++q)
                reds[wv][mi * 16 + ((lane >> 4) << 2) + q] = rs[mi][q];
    }
    __syncthreads();
#pragma unroll
    for (int mi = 0; mi < 4; ++mi)
#pragma unroll
        for (int q = 0; q < 4; ++q) {
            int row = mi * 16 + ((lane >> 4) << 2) + q;
            float st = (reds[0][row] + reds[1][row]) + (reds[2][row] + reds[3][row]);
            rm[mi][q] = rm[mi][q] + logf(st);   // lse
        }
    // write logprobs (in place over H) and boosted probs to LDS
#pragma unroll
    for (int mi = 0; mi < 4; ++mi)
#pragma unroll
        for (int q = 0; q < 4; ++q) {
            int row = mi * 16 + ((lane >> 4) << 2) + q;
#pragma unroll
            for (int ni = 0; ni < 8; ++ni) {
                int col = wv * 128 + ni * 16 + (lane & 15);
                float lpv = acc[mi][ni][q] - rm[mi][q];
                lp[(size_t)(r0 + row) * 512 + col] = lpv;
                SH[row * 520 + col] = bf16r(expf(lpv) * BOOST);
            }
        }
    __syncthreads();
    // gather: thread j writes target-prob column j for all 64 rows; coalesced
    const int tgj = s_tg[tid];
#pragma unroll 4
    for (int r = 0; r < 64; ++r)
        P[(size_t)(r0 + r) * PSTRIDE + tid] = SH[r * 520 + tgj];
    if (tid < 64)
        P[(size_t)(r0 + tid) * PSTRIDE + 256] = SH[tid * 520 + BLANKI];
}

// ---------------------------------------------------------------------------
// CTC forward-only DP, f32, depth-16 named-register pipeline (R9 structure),
// unconditional power-of-2 rescale every 8 steps (growth <= 2^109 < 2^127;
// boosted probs drift alpha upward; window semantics proven in R4/R5).
// Lane l owns states 8l..8l+7; lane 63 also state 512. 32 blocks, 1 wave.
// ---------------------------------------------------------------------------
struct Pr5 { float pb, p1, p3, p5, p7; };

__device__ __forceinline__ Pr5 ldrowf(const unsigned short* rp, int l)
{
    ushort4 q = *(const ushort4*)(rp + 4 * l);
    Pr5 r;
    r.pb = bf2f(rp[256]);
    r.p1 = bf2f(q.x); r.p3 = bf2f(q.y); r.p5 = bf2f(q.z); r.p7 = bf2f(q.w);
    return r;
}

#define REP8A(OP) OP(0) OP(1) OP(2) OP(3) OP(4) OP(5) OP(6) OP(7)
#define REP8B(OP) OP(8) OP(9) OP(10) OP(11) OP(12) OP(13) OP(14) OP(15)
#define REP16(OP) REP8A(OP) REP8B(OP)

__global__ __launch_bounds__(64) void ctc_fwd(
    const unsigned short* __restrict__ P,
    const int* __restrict__ enc_mask, const int* __restrict__ targets,
    const int* __restrict__ tgt_mask,
    float* __restrict__ out_len_f, float* __restrict__ per_sample,
    int* __restrict__ tl_out)
{
    const int b = blockIdx.x;
    const int l = threadIdx.x;

    int se = 0, st = 0;
    {
        const int* em = enc_mask + (size_t)b * SSRC;
#pragma unroll
        for (int i = 0; i < 8; ++i) se += (em[i * 64 + l] != 0) ? 1 : 0;
        const int* tm = tgt_mask + (size_t)b * L_;
#pragma unroll
        for (int i = 0; i < 4; ++i) st += (tm[i * 64 + l] != 0) ? 1 : 0;
#pragma unroll
        for (int off = 32; off; off >>= 1) {
            se += __shfl_xor(se, off);
            st += __shfl_xor(st, off);
        }
    }
    const int tl = st;
    const int IL = STRIDE_ * se;

    const int4 tg = ((const int4*)(targets + (size_t)b * L_))[l];
    int prevw = __shfl_up(tg.w, 1);
    if (l == 0) prevw = BLANKI;
    const bool k1 = (tg.x != BLANKI) && (tg.x != prevw);
    const bool k3 = (tg.y != BLANKI) && (tg.y != tg.x);
    const bool k5 = (tg.z != BLANKI) && (tg.z != tg.y);
    const bool k7 = (tg.w != BLANKI) && (tg.w != tg.z);

    const unsigned short* Pb = P + (size_t)b * T_ * PSTRIDE;

    float a0 = 0, a1 = 0, a2 = 0, a3 = 0, a4 = 0, a5 = 0, a6 = 0, a7 = 0, a8 = 0;
    int Ei = 0;

    auto rescale9 = [&]() {
        float m = fmaxf(fmaxf(fmaxf(a0, a1), fmaxf(a2, a3)),
                        fmaxf(fmaxf(a4, a5), fmaxf(fmaxf(a6, a7), a8)));
        int e = (int)((__float_as_uint(m) >> 23) & 0xffu);
#pragma unroll
        for (int off = 1; off < 64; off <<= 1) {
            int o = __shfl_xor(e, off);
            e = o > e ? o : e;
        }
        float sc = __uint_as_float((unsigned)(254 - e) << 23);   // 2^(127-e)
        Ei += e - 127;
        a0 *= sc; a1 *= sc; a2 *= sc; a3 *= sc; a4 *= sc;
        a5 *= sc; a6 *= sc; a7 *= sc; a8 *= sc;
    };

    if (l == 0) {
        a0 = bf2f(Pb[256]);
        if (tl > 0) a1 = bf2f(Pb[0]);
    }
    auto fstep = [&](const Pr5& r) {
        float u1 = __shfl_up(a7, 1);
        if (l == 0) u1 = 0.f;
        float n0 = (a0 + u1) * r.pb;
        float n1 = (a0 + a1 + (k1 ? u1 : 0.f)) * r.p1;
        float n2 = (a1 + a2) * r.pb;
        float n3 = (a2 + a3 + (k3 ? a1 : 0.f)) * r.p3;
        float n4 = (a3 + a4) * r.pb;
        float n5 = (a4 + a5 + (k5 ? a3 : 0.f)) * r.p5;
        float n6 = (a5 + a6) * r.pb;
        float n7 = (a6 + a7 + (k7 ? a5 : 0.f)) * r.p7;
        float n8 = (l == 63) ? (a7 + a8) * r.pb : 0.f;
        a0 = n0; a1 = n1; a2 = n2; a3 = n3; a4 = n4;
        a5 = n5; a6 = n6; a7 = n7; a8 = n8;
    };
    const int nst = IL - 1;
    if (nst > 0) {
        Pr5 q0, q1, q2, q3, q4, q5, q6, q7, q8, q9, q10, q11, q12, q13, q14, q15;
#define LDI(i) { int ti = 1 + i; if (ti > nst) ti = nst; \
                 q##i = ldrowf(Pb + (size_t)ti * PSTRIDE, l); }
        REP16(LDI)
#undef LDI
        int t = 1;
        while (t + 15 <= nst) {
#define STP(i) { fstep(q##i); int ti = t + 16 + i; if (ti > nst) ti = nst; \
                 q##i = ldrowf(Pb + (size_t)ti * PSTRIDE, l); }
            REP8A(STP)
            rescale9();
            REP8B(STP)
#undef STP
            rescale9();
            t += 16;
        }
        int rem = nst - t + 1;   // 0..15
#define TLS(i) if (i < rem) fstep(q##i);
        REP8A(TLS)
        rescale9();
#define TLS2(i) if (i < rem) fstep(q##i);
        REP8B(TLS2)
#undef TLS2
#undef TLS
    }
    rescale9();

    __shared__ float as_[S_];
    as_[l * 8 + 0] = a0; as_[l * 8 + 1] = a1; as_[l * 8 + 2] = a2; as_[l * 8 + 3] = a3;
    as_[l * 8 + 4] = a4; as_[l * 8 + 5] = a5; as_[l * 8 + 6] = a6; as_[l * 8 + 7] = a7;
    if (l == 63) as_[512] = a8;
    __syncthreads();
    if (l == 0) {
        int i2 = 2 * tl;
        float al = as_[i2];
        float ap = (tl > 0) ? as_[i2 - 1] : 0.f;
        float s = al + ap;
        per_sample[b] = -(logf(s) +
            (float)(Ei - BOOST_BITS * IL) * 0.69314718055994531f);
        tl_out[b] = tl;
        out_len_f[b] = (float)IL;
    }
}

__global__ __launch_bounds__(64) void ctc_loss_final(
    const float* __restrict__ per_sample, const int* __restrict__ tl,
    float* __restrict__ out_loss)
{
    int tid = threadIdx.x;
    float v = 0.f;
    if (tid < B_) {
        int t = tl[tid] < 1 ? 1 : tl[tid];
        v = per_sample[tid] / (float)t;
    }
#pragma unroll
    for (int off = 32; off; off >>= 1) v += __shfl_down(v, off);
    if (tid == 0) {
        float loss = v / (float)B_;
        if (isnan(loss) || isinf(loss)) loss = 0.f;
        *out_loss = loss;
    }
}

// ---------------------------------------------------------------------------
extern "C" void kernel_launch(void* const* d_in, const int* in_sizes, int n_in,
                              void* d_out, int out_size, void* d_ws, size_t ws_size,
                              hipStream_t stream)
{
    (void)in_sizes; (void)n_in; (void)out_size; (void)ws_size;

    const float* rep      = (const float*)d_in[0];
    const int*   enc_mask = (const int*)d_in[1];
    const int*   targets  = (const int*)d_in[2];
    const int*   tgt_mask = (const int*)d_in[3];
    const float* W_exp    = (const float*)d_in[4];
    const float* b_exp    = (const float*)d_in[5];
    const float* W1       = (const float*)d_in[6];
    const float* b1       = (const float*)d_in[7];
    const float* W2       = (const float*)d_in[8];
    const float* b2       = (const float*)d_in[9];

    float* out       = (float*)d_out;
    float* logprobs  = out;                          // [65536][512] f32
    float* out_len_f = out + (size_t)B_ * T_ * V_;
    float* out_loss  = out_len_f + B_;
    // H (bf16 [65536][1024]) lives in the logprobs bytes: exactly 128 MB.
    unsigned short* Hd = (unsigned short*)d_out;

    // ws layout (~38.7 MB, under the 39.2 MB proven in R7-R9):
    unsigned short* WcT = (unsigned short*)d_ws;                  // [4096][512] bf16, 4 MB
    float* bc           = (float*)(WcT + (size_t)4096 * 512);     // [4096]
    float* per_sample   = bc + 4096;                              // [64]
    int*   tl_out       = (int*)(per_sample + 64);                // [64]
    unsigned short* P   = (unsigned short*)(tl_out + 64);         // [65536][264], 34.6 MB
    // aliased inside P (all dead before gemm2_lsm writes P):
    unsigned short* repb   = P;                                   // [16384][512]
    unsigned short* W_expb = P + (size_t)16384 * 512;             // [512][2048]
    unsigned short* W1T    = W_expb + (size_t)512 * 2048;         // [1024][512]
    // W2T reuses WcT (WcT dead after gemm1):
    unsigned short* W2T = WcT;                                    // [512][1024]

    // 1) conversions
    cvt_f32_bf16<<<8192, 256, 0, stream>>>(rep, repb, (16384 * 512) / 4);
    cvt_f32_bf16<<<1024, 256, 0, stream>>>(W_exp, W_expb, (512 * 2048) / 4);
    transpose_cvt<<<dim3(32, 16), dim3(32, 8), 0, stream>>>(W1, W1T, 512, 1024);

    // 2) fold via MFMA: WcT[(k*1024+h)][e] = sum_d W1T[h][d] * W_exp[e][k*512+d]
    gemm_mfma<false, true, false><<<dim3(4, 8, 4), 256, 0, stream>>>(
        W1T, 512, 0, W_expb, 2048, 512, WcT, 512, (long)1024 * 512, nullptr, 512);
    combine_bias<<<16, 256, 0, stream>>>(b_exp, W1, b1, bc);

    // 3) GEMM1 (single launch): H = relu(rep @ Wc + bc) bf16 -> d_out
    gemm_mfma<true, true, true><<<dim3(32, 128), 256, 0, stream>>>(
        repb, 512, 0, WcT, 512, 0, Hd, 4096, 0, bc, 512);

    // 4) W2 -> W2T (into the now-dead WcT region)
    transpose_cvt<<<dim3(16, 32), dim3(32, 8), 0, stream>>>(W2, W2T, 1024, 512);

    // 5) fused GEMM2 + log_softmax + gather (in-place logprobs over H)
    gemm2_lsm<<<1024, 256, 0, stream>>>(Hd, W2T, b2, targets, logprobs, P);

    // 6) CTC forward DP + loss
    ctc_fwd<<<B_, 64, 0, stream>>>(P, enc_mask, targets, tgt_mask,
                                   out_len_f, per_sample, tl_out);
    ctc_loss_final<<<1, 64, 0, stream>>>(per_sample, tl_out, out_loss);
}

// Round 11
// 560.429 us; speedup vs baseline: 1.1142x; 1.1142x over previous
//
#include <hip/hip_runtime.h>
#include <math.h>

#define B_ 32
#define SSRC 512
#define D_ 512
#define STRIDE_ 4
#define V_ 512
#define L_ 256
#define T_ (SSRC * STRIDE_)   // 2048
#define S_ (2 * L_ + 1)       // 513
#define BLANKI 1
#define PSTRIDE 264           // compact prob row stride (ushorts)
#define BOOST 4096.0f         // 2^12 pre-boost on gathered probs
#define BOOST_BITS 12

typedef __attribute__((ext_vector_type(8))) short bf16x8;
typedef __attribute__((ext_vector_type(4))) float f32x4;

__device__ __forceinline__ unsigned short bf16r(float x) {
    unsigned u = __float_as_uint(x);
    return (unsigned short)((u + 0x7fffu + ((u >> 16) & 1u)) >> 16);
}
__device__ __forceinline__ float bf2f(unsigned short u) {
    return __uint_as_float((unsigned)u << 16);
}
__device__ __forceinline__ void gl_lds16(const unsigned short* g, unsigned short* l) {
    __builtin_amdgcn_global_load_lds(
        (const __attribute__((address_space(1))) unsigned int*)g,
        (__attribute__((address_space(3))) unsigned int*)l, 16, 0, 0);
}

// ---------------------------------------------------------------------------
__global__ __launch_bounds__(256) void combine_bias(
    const float* __restrict__ b_exp, const float* __restrict__ W1,
    const float* __restrict__ b1, float* __restrict__ bc)
{
    int j = blockIdx.x * 256 + threadIdx.x;
    int k = j >> 10, h = j & 1023;
    float s = b1[h];
    const float* be = b_exp + k * 512;
    for (int d = 0; d < 512; ++d)
        s = fmaf(be[d], W1[d * 1024 + h], s);
    bc[j] = s;
}

// ---------------------------------------------------------------------------
__global__ __launch_bounds__(256) void transpose_cvt(
    const float* __restrict__ in, unsigned short* __restrict__ out, int R, int C)
{
    __shared__ float tile[32][33];
    int bx = blockIdx.x * 32, by = blockIdx.y * 32;
    int tx = threadIdx.x, ty = threadIdx.y;
#pragma unroll
    for (int i = 0; i < 32; i += 8)
        tile[ty + i][tx] = in[(size_t)(by + ty + i) * C + bx + tx];
    __syncthreads();
#pragma unroll
    for (int i = 0; i < 32; i += 8)
        out[(size_t)(bx + ty + i) * R + by + tx] = bf16r(tile[tx][ty + i]);
}

__global__ __launch_bounds__(256) void cvt_f32_bf16(
    const float* __restrict__ in, unsigned short* __restrict__ out, int n4)
{
    int i = blockIdx.x * 256 + threadIdx.x;
    if (i >= n4) return;
    float4 v = ((const float4*)in)[i];
    ushort4 o;
    o.x = bf16r(v.x); o.y = bf16r(v.y); o.z = bf16r(v.z); o.w = bf16r(v.w);
    ((ushort4*)out)[i] = o;
}

// ---------------------------------------------------------------------------
// bf16 MFMA GEMM (m97 structure) + bijective XCD swizzle (nwg % 8 == 0).
// Optional gridDim.z slicing via element offsets zA/zBT/zC.
// ---------------------------------------------------------------------------
template <bool RELU, bool OUTBF16, bool BIAS>
__global__ __launch_bounds__(256) void gemm_mfma(
    const unsigned short* __restrict__ A, int lda, long zA,
    const unsigned short* __restrict__ BT, int ldb, long zBT,
    void* __restrict__ Cvoid, int ldc, long zC,
    const float* __restrict__ bias, int K)
{
    __shared__ unsigned short As[2][128][32];
    __shared__ unsigned short Bs[2][128][32];
    const int tid = threadIdx.x;
    const int wid = tid >> 6, lane = tid & 63;

    A  += (size_t)blockIdx.z * zA;
    BT += (size_t)blockIdx.z * zBT;
    unsigned short* Cb = OUTBF16 ? ((unsigned short*)Cvoid + (size_t)blockIdx.z * zC) : nullptr;
    float*          Cf = OUTBF16 ? nullptr : ((float*)Cvoid + (size_t)blockIdx.z * zC);

    const int gx = gridDim.x;
    int wg = blockIdx.y * gx + blockIdx.x;
    const int q = (gx * gridDim.y) >> 3;
    wg = (wg & 7) * q + (wg >> 3);
    const int bm = (wg / gx) * 128, bn = (wg % gx) * 128;

    const int wm = (wid >> 1) * 64, wn = (wid & 1) * 64;

    f32x4 acc[4][4] = {};
    const int r_in = lane >> 2;
    const int cch = (lane & 3) * 8;
    const int rbase = wid * 32;

    auto stage = [&](int buf, int k0) {
#pragma unroll
        for (int i = 0; i < 2; ++i) {
            int rloc = rbase + i * 16;
            gl_lds16(A  + (size_t)(bm + rloc + r_in) * lda + k0 + cch, &As[buf][rloc][0]);
            gl_lds16(BT + (size_t)(bn + rloc + r_in) * ldb + k0 + cch, &Bs[buf][rloc][0]);
        }
    };

    const int nt = K / 32;
    stage(0, 0);
    for (int t = 0; t < nt; ++t) {
        int cur = t & 1;
        __syncthreads();
        if (t + 1 < nt) stage(cur ^ 1, (t + 1) * 32);
        bf16x8 af[4], bfr[4];
#pragma unroll
        for (int mi = 0; mi < 4; ++mi)
            af[mi] = *(const bf16x8*)&As[cur][wm + mi * 16 + (lane & 15)][(lane >> 4) * 8];
#pragma unroll
        for (int ni = 0; ni < 4; ++ni)
            bfr[ni] = *(const bf16x8*)&Bs[cur][wn + ni * 16 + (lane & 15)][(lane >> 4) * 8];
#pragma unroll
        for (int mi = 0; mi < 4; ++mi)
#pragma unroll
            for (int ni = 0; ni < 4; ++ni)
                acc[mi][ni] = __builtin_amdgcn_mfma_f32_16x16x32_bf16(
                    af[mi], bfr[ni], acc[mi][ni], 0, 0, 0);
    }

#pragma unroll
    for (int ni = 0; ni < 4; ++ni) {
        int gcol = bn + wn + ni * 16 + (lane & 15);
        float bv = BIAS ? bias[gcol] : 0.f;
#pragma unroll
        for (int mi = 0; mi < 4; ++mi) {
#pragma unroll
            for (int q2 = 0; q2 < 4; ++q2) {
                int grow = bm + wm + mi * 16 + ((lane >> 4) << 2) + q2;
                float x = acc[mi][ni][q2] + bv;
                if (RELU) x = fmaxf(x, 0.f);
                if (OUTBF16)
                    Cb[(size_t)grow * ldc + gcol] = bf16r(x);
                else
                    Cf[(size_t)grow * ldc + gcol] = x;
            }
        }
    }
}

// ---------------------------------------------------------------------------
// Fused GEMM2 + log_softmax, v2 (occupancy-first). One block = 32 logits
// rows x V=512 (full row => block-local softmax). A = H [65536][1024] bf16
// in d_out; lp f32 written IN-PLACE over the same rows (block-self-contained).
// A staged in 4KB dbuf LDS; B-frags loaded straight from global W2T (1 MB,
// L2-resident) with register double-buffer. 4 waves; wave wv owns 128 cols.
// acc[2][8] = 64 VGPR -> ~3 waves/SIMD (R10 fused version: 76.8KB LDS,
// VGPR 196, occupancy 11.6%, 7.4M LDS conflicts -> 261us).
// ---------------------------------------------------------------------------
__global__ __launch_bounds__(256) void gemm2_lsm(
    const unsigned short* __restrict__ H,     // [65536][1024] bf16 (= d_out)
    const unsigned short* __restrict__ W2T,   // [512][1024] bf16
    const float* __restrict__ b2,             // [512]
    float* __restrict__ lp)                   // [65536][512] f32 (= d_out)
{
    __shared__ unsigned short As[2][32][32];  // 4 KB
    __shared__ float redm[4][32], reds[4][32];

    const int tid = threadIdx.x;
    const int wv = tid >> 6, lane = tid & 63;
    const int r0 = blockIdx.x * 32;

    // A staging: 32 rows x 32 k = 2KB/buf; waves 0,1 each cover 16 rows.
    auto stageA = [&](int buf, int k0) {
        if (wv < 2) {
            int rr = wv * 16;
            gl_lds16(H + (size_t)(r0 + rr + (lane >> 2)) * 1024 + k0 + (lane & 3) * 8,
                     &As[buf][rr][0]);
        }
    };

    // B fragment pointers (per ni): row = wv*128 + ni*16 + (lane&15), k-base (lane>>4)*8
    const unsigned short* bptr[8];
#pragma unroll
    for (int ni = 0; ni < 8; ++ni)
        bptr[ni] = W2T + (size_t)(wv * 128 + ni * 16 + (lane & 15)) * 1024 + (lane >> 4) * 8;

    f32x4 acc[2][8] = {};
    bf16x8 bfr[2][8];
#pragma unroll
    for (int ni = 0; ni < 8; ++ni) bfr[0][ni] = *(const bf16x8*)(bptr[ni]);
    stageA(0, 0);

#pragma unroll
    for (int t = 0; t < 32; ++t) {
        const int cur = t & 1;
        __syncthreads();
        if (t + 1 < 32) {
            stageA(cur ^ 1, (t + 1) * 32);
#pragma unroll
            for (int ni = 0; ni < 8; ++ni)
                bfr[cur ^ 1][ni] = *(const bf16x8*)(bptr[ni] + (size_t)(t + 1) * 32);
        }
        bf16x8 af0 = *(const bf16x8*)&As[cur][lane & 15][(lane >> 4) * 8];
        bf16x8 af1 = *(const bf16x8*)&As[cur][16 + (lane & 15)][(lane >> 4) * 8];
#pragma unroll
        for (int ni = 0; ni < 8; ++ni) {
            acc[0][ni] = __builtin_amdgcn_mfma_f32_16x16x32_bf16(af0, bfr[cur][ni], acc[0][ni], 0, 0, 0);
            acc[1][ni] = __builtin_amdgcn_mfma_f32_16x16x32_bf16(af1, bfr[cur][ni], acc[1][ni], 0, 0, 0);
        }
    }

    // ---- epilogue: bias + block-local row softmax + in-place lp write ----
    float bcol[8];
#pragma unroll
    for (int ni = 0; ni < 8; ++ni) bcol[ni] = b2[wv * 128 + ni * 16 + (lane & 15)];
#pragma unroll
    for (int mi = 0; mi < 2; ++mi)
#pragma unroll
        for (int ni = 0; ni < 8; ++ni)
#pragma unroll
            for (int q = 0; q < 4; ++q) acc[mi][ni][q] += bcol[ni];

    float rm[2][4];
#pragma unroll
    for (int mi = 0; mi < 2; ++mi)
#pragma unroll
        for (int q = 0; q < 4; ++q) {
            float m = acc[mi][0][q];
#pragma unroll
            for (int ni = 1; ni < 8; ++ni) m = fmaxf(m, acc[mi][ni][q]);
#pragma unroll
            for (int off = 1; off < 16; off <<= 1) m = fmaxf(m, __shfl_xor(m, off));
            rm[mi][q] = m;
        }
    if ((lane & 15) == 0) {
#pragma unroll
        for (int mi = 0; mi < 2; ++mi)
#pragma unroll
            for (int q = 0; q < 4; ++q)
                redm[wv][mi * 16 + ((lane >> 4) << 2) + q] = rm[mi][q];
    }
    __syncthreads();
#pragma unroll
    for (int mi = 0; mi < 2; ++mi)
#pragma unroll
        for (int q = 0; q < 4; ++q) {
            int row = mi * 16 + ((lane >> 4) << 2) + q;
            rm[mi][q] = fmaxf(fmaxf(redm[0][row], redm[1][row]),
                              fmaxf(redm[2][row], redm[3][row]));
        }
    float rs[2][4];
#pragma unroll
    for (int mi = 0; mi < 2; ++mi)
#pragma unroll
        for (int q = 0; q < 4; ++q) {
            float s = 0.f;
#pragma unroll
            for (int ni = 0; ni < 8; ++ni) s += expf(acc[mi][ni][q] - rm[mi][q]);
#pragma unroll
            for (int off = 1; off < 16; off <<= 1) s += __shfl_xor(s, off);
            rs[mi][q] = s;
        }
    if ((lane & 15) == 0) {
#pragma unroll
        for (int mi = 0; mi < 2; ++mi)
#pragma unroll
            for (int q = 0; q < 4; ++q)
                reds[wv][mi * 16 + ((lane >> 4) << 2) + q] = rs[mi][q];
    }
    __syncthreads();
#pragma unroll
    for (int mi = 0; mi < 2; ++mi)
#pragma unroll
        for (int q = 0; q < 4; ++q) {
            int row = mi * 16 + ((lane >> 4) << 2) + q;
            float st = (reds[0][row] + reds[1][row]) + (reds[2][row] + reds[3][row]);
            float lse = rm[mi][q] + logf(st);
#pragma unroll
            for (int ni = 0; ni < 8; ++ni) {
                int col = wv * 128 + ni * 16 + (lane & 15);
                lp[(size_t)(r0 + row) * 512 + col] = acc[mi][ni][q] - lse;
            }
        }
}

// ---------------------------------------------------------------------------
// Streaming gather: P[w][j] = bf16(exp(lp[w][tg_j])*BOOST), P[w][256] = blank.
// One wave per row, 4 waves/block; wave-private 1KB LDS prob row.
// ---------------------------------------------------------------------------
__global__ __launch_bounds__(256) void gather_p(
    const float* __restrict__ lp, const int* __restrict__ targets,
    unsigned short* __restrict__ P)
{
    const int w = (blockIdx.x << 2) + (threadIdx.x >> 6);
    const int l = threadIdx.x & 63;
    const int wl = threadIdx.x >> 6;
    const int b = w >> 11;

    __shared__ unsigned short pr[4][512];
    const float* row = lp + (size_t)w * 512;
    float4 v0 = ((const float4*)row)[l];
    float4 v1 = ((const float4*)row)[64 + l];
    pr[wl][l * 4 + 0] = bf16r(expf(v0.x) * BOOST);
    pr[wl][l * 4 + 1] = bf16r(expf(v0.y) * BOOST);
    pr[wl][l * 4 + 2] = bf16r(expf(v0.z) * BOOST);
    pr[wl][l * 4 + 3] = bf16r(expf(v0.w) * BOOST);
    pr[wl][256 + l * 4 + 0] = bf16r(expf(v1.x) * BOOST);
    pr[wl][256 + l * 4 + 1] = bf16r(expf(v1.y) * BOOST);
    pr[wl][256 + l * 4 + 2] = bf16r(expf(v1.z) * BOOST);
    pr[wl][256 + l * 4 + 3] = bf16r(expf(v1.w) * BOOST);
    __syncthreads();

    int4 tg = ((const int4*)(targets + (size_t)b * L_))[l];
    ushort4 o;
    o.x = pr[wl][tg.x]; o.y = pr[wl][tg.y]; o.z = pr[wl][tg.z]; o.w = pr[wl][tg.w];
    *(ushort4*)&P[(size_t)w * PSTRIDE + l * 4] = o;
    if (l == 0) P[(size_t)w * PSTRIDE + 256] = pr[wl][BLANKI];
}

// ---------------------------------------------------------------------------
// CTC forward/backward DP split, f64, depth-16 NAMED-register pipeline
// (R9 structure, measured 148.8us). Rescale once per 16 steps.
// Lane l owns states 8l..8l+7; lane 63 also state 512.
// ---------------------------------------------------------------------------
struct Pr5 { float pb, p1, p3, p5, p7; };

__device__ __forceinline__ Pr5 ldrowf(const unsigned short* rp, int l)
{
    ushort4 q = *(const ushort4*)(rp + 4 * l);
    Pr5 r;
    r.pb = bf2f(rp[256]);
    r.p1 = bf2f(q.x); r.p3 = bf2f(q.y); r.p5 = bf2f(q.z); r.p7 = bf2f(q.w);
    return r;
}

#define REP16(OP) OP(0) OP(1) OP(2) OP(3) OP(4) OP(5) OP(6) OP(7) \
                  OP(8) OP(9) OP(10) OP(11) OP(12) OP(13) OP(14) OP(15)

__global__ __launch_bounds__(64) void ctc_fwd_bwd(
    const unsigned short* __restrict__ P,
    const int* __restrict__ enc_mask, const int* __restrict__ targets,
    const int* __restrict__ tgt_mask,
    float* __restrict__ out_len_f,
    double* __restrict__ AV, double* __restrict__ BV,
    int* __restrict__ EF, int* __restrict__ EB,
    int* __restrict__ ILv, int* __restrict__ tl_out)
{
    const int b = blockIdx.x & 31;
    const bool isf = blockIdx.x < 32;
    const int l = threadIdx.x;

    int se = 0, st = 0;
    {
        const int* em = enc_mask + (size_t)b * SSRC;
#pragma unroll
        for (int i = 0; i < 8; ++i) se += (em[i * 64 + l] != 0) ? 1 : 0;
        const int* tm = tgt_mask + (size_t)b * L_;
#pragma unroll
        for (int i = 0; i < 4; ++i) st += (tm[i * 64 + l] != 0) ? 1 : 0;
#pragma unroll
        for (int off = 32; off; off >>= 1) {
            se += __shfl_xor(se, off);
            st += __shfl_xor(st, off);
        }
    }
    const int tl = st;
    const int IL = STRIDE_ * se;
    const int h = (IL > 0) ? ((IL - 1) >> 1) : 0;

    const int4 tg = ((const int4*)(targets + (size_t)b * L_))[l];
    int prevw = __shfl_up(tg.w, 1);
    if (l == 0) prevw = BLANKI;
    const bool k1 = (tg.x != BLANKI) && (tg.x != prevw);
    const bool k3 = (tg.y != BLANKI) && (tg.y != tg.x);
    const bool k5 = (tg.z != BLANKI) && (tg.z != tg.y);
    const bool k7 = (tg.w != BLANKI) && (tg.w != tg.z);

    const unsigned short* Pb = P + (size_t)b * T_ * PSTRIDE;

    double a0 = 0, a1 = 0, a2 = 0, a3 = 0, a4 = 0, a5 = 0, a6 = 0, a7 = 0, a8 = 0;
    int Ei = 0;

    auto rescale9 = [&]() {
        double m = fmax(fmax(fmax(a0, a1), fmax(a2, a3)),
                        fmax(fmax(a4, a5), fmax(fmax(a6, a7), a8)));
        int e = (int)((__double_as_longlong(m) >> 52) & 0x7ff);
#pragma unroll
        for (int off = 1; off < 64; off <<= 1) {
            int o = __shfl_xor(e, off);
            e = o > e ? o : e;
        }
        int sh = 1023 - e;
        double sc = __longlong_as_double(((long long)(sh + 1023)) << 52);
        Ei += e - 1023;
        a0 *= sc; a1 *= sc; a2 *= sc; a3 *= sc; a4 *= sc;
        a5 *= sc; a6 *= sc; a7 *= sc; a8 *= sc;
    };

    if (isf) {
        if (l == 0) {
            a0 = (double)bf2f(Pb[256]);
            if (tl > 0) a1 = (double)bf2f(Pb[0]);
        }
        auto fstep = [&](const Pr5& r) {
            double pb = (double)r.pb, p1 = (double)r.p1, p3 = (double)r.p3;
            double p5 = (double)r.p5, p7 = (double)r.p7;
            double u1 = __shfl_up(a7, 1);
            if (l == 0) u1 = 0.0;
            double n0 = (a0 + u1) * pb;
            double n1 = (a0 + a1 + (k1 ? u1 : 0.0)) * p1;
            double n2 = (a1 + a2) * pb;
            double n3 = (a2 + a3 + (k3 ? a1 : 0.0)) * p3;
            double n4 = (a3 + a4) * pb;
            double n5 = (a4 + a5 + (k5 ? a3 : 0.0)) * p5;
            double n6 = (a5 + a6) * pb;
            double n7 = (a6 + a7 + (k7 ? a5 : 0.0)) * p7;
            double n8 = (l == 63) ? (a7 + a8) * pb : 0.0;
            a0 = n0; a1 = n1; a2 = n2; a3 = n3; a4 = n4;
            a5 = n5; a6 = n6; a7 = n7; a8 = n8;
        };
        const int nst = h;
        if (nst > 0) {
            Pr5 q0, q1, q2, q3, q4, q5, q6, q7, q8, q9, q10, q11, q12, q13, q14, q15;
#define LDI(i) { int ti = 1 + i; if (ti > nst) ti = nst; \
                 q##i = ldrowf(Pb + (size_t)ti * PSTRIDE, l); }
            REP16(LDI)
#undef LDI
            int t = 1;
            while (t + 15 <= nst) {
#define STP(i) { fstep(q##i); int ti = t + 16 + i; if (ti > nst) ti = nst; \
                 q##i = ldrowf(Pb + (size_t)ti * PSTRIDE, l); }
                REP16(STP)
#undef STP
                rescale9();
                t += 16;
            }
            int rem = nst - t + 1;
#define TLS(i) if (i < rem) fstep(q##i);
            REP16(TLS)
#undef TLS
        }
        rescale9();
        double* av = AV + b * 520;
        av[l * 8 + 0] = a0; av[l * 8 + 1] = a1; av[l * 8 + 2] = a2; av[l * 8 + 3] = a3;
        av[l * 8 + 4] = a4; av[l * 8 + 5] = a5; av[l * 8 + 6] = a6; av[l * 8 + 7] = a7;
        if (l == 63) av[512] = a8;
        if (l == 0) {
            EF[b] = Ei; ILv[b] = IL; tl_out[b] = tl;
            out_len_f[b] = (float)IL;
        }
    } else {
        {
            int s0 = l * 8;
            int e0 = 2 * tl, e1 = 2 * tl - 1;
            a0 = (s0 + 0 == e0 || (tl > 0 && s0 + 0 == e1)) ? 1.0 : 0.0;
            a1 = (s0 + 1 == e0 || (tl > 0 && s0 + 1 == e1)) ? 1.0 : 0.0;
            a2 = (s0 + 2 == e0 || (tl > 0 && s0 + 2 == e1)) ? 1.0 : 0.0;
            a3 = (s0 + 3 == e0 || (tl > 0 && s0 + 3 == e1)) ? 1.0 : 0.0;
            a4 = (s0 + 4 == e0 || (tl > 0 && s0 + 4 == e1)) ? 1.0 : 0.0;
            a5 = (s0 + 5 == e0 || (tl > 0 && s0 + 5 == e1)) ? 1.0 : 0.0;
            a6 = (s0 + 6 == e0 || (tl > 0 && s0 + 6 == e1)) ? 1.0 : 0.0;
            a7 = (s0 + 7 == e0 || (tl > 0 && s0 + 7 == e1)) ? 1.0 : 0.0;
            if (l == 63) a8 = (512 == e0) ? 1.0 : 0.0;
        }
        float knff = __shfl_down(k1 ? 1.f : 0.f, 1);
        if (l == 63) knff = 0.f;
        const double knf = (double)knff;
        auto bstep = [&](const Pr5& r) {
            double pb = (double)r.pb, p1 = (double)r.p1, p3 = (double)r.p3;
            double p5 = (double)r.p5, p7 = (double)r.p7;
            double g0 = a0 * pb, g1 = a1 * p1, g2 = a2 * pb, g3 = a3 * p3;
            double g4 = a4 * pb, g5 = a5 * p5, g6 = a6 * pb, g7 = a7 * p7;
            double g8 = (l == 63) ? a8 * pb : 0.0;
            double d1 = __shfl_down(g0, 1);
            double d2 = __shfl_down(g1, 1);
            if (l == 63) { d1 = g8; d2 = 0.0; }
            double m0 = g0 + g1;
            double m1 = g1 + g2 + (k3 ? g3 : 0.0);
            double m2 = g2 + g3;
            double m3 = g3 + g4 + (k5 ? g5 : 0.0);
            double m4 = g4 + g5;
            double m5 = g5 + g6 + (k7 ? g7 : 0.0);
            double m6 = g6 + g7;
            double m7 = g7 + d1 + knf * d2;
            double m8 = (l == 63) ? g8 : 0.0;
            a0 = m0; a1 = m1; a2 = m2; a3 = m3; a4 = m4;
            a5 = m5; a6 = m6; a7 = m7; a8 = m8;
        };
        const int nbs = IL - 1 - h;
        if (nbs > 0) {
            const int rmin = h + 1;
            Pr5 q0, q1, q2, q3, q4, q5, q6, q7, q8, q9, q10, q11, q12, q13, q14, q15;
#define LDB(i) { int ri = IL - 1 - i; if (ri < rmin) ri = rmin; \
                 q##i = ldrowf(Pb + (size_t)ri * PSTRIDE, l); }
            REP16(LDB)
#undef LDB
            int j = 0;
            while (j + 16 <= nbs) {
#define STB(i) { bstep(q##i); int ri = IL - 1 - (j + 16 + i); if (ri < rmin) ri = rmin; \
                 q##i = ldrowf(Pb + (size_t)ri * PSTRIDE, l); }
                REP16(STB)
#undef STB
                rescale9();
                j += 16;
            }
            int rem = nbs - j;
#define TLB(i) if (i < rem) bstep(q##i);
            REP16(TLB)
#undef TLB
        }
        rescale9();
        double* bv = BV + b * 520;
        bv[l * 8 + 0] = a0; bv[l * 8 + 1] = a1; bv[l * 8 + 2] = a2; bv[l * 8 + 3] = a3;
        bv[l * 8 + 4] = a4; bv[l * 8 + 5] = a5; bv[l * 8 + 6] = a6; bv[l * 8 + 7] = a7;
        if (l == 63) bv[512] = a8;
        if (l == 0) EB[b] = Ei;
    }
}

// ---------------------------------------------------------------------------
__global__ __launch_bounds__(64) void ctc_combine(
    const double* __restrict__ AV, const double* __restrict__ BV,
    const int* __restrict__ EF, const int* __restrict__ EB,
    const int* __restrict__ ILv, float* __restrict__ per_sample)
{
    const int b = blockIdx.x, l = threadIdx.x;
    const double* av = AV + b * 520;
    const double* bv = BV + b * 520;
    double s = 0.0;
#pragma unroll
    for (int i = 0; i < 8; ++i)
        s += av[l * 8 + i] * bv[l * 8 + i];
    if (l == 63) s += av[512] * bv[512];
#pragma unroll
    for (int off = 1; off < 64; off <<= 1) s += __shfl_xor(s, off);
    if (l == 0) {
        double lg = log(s) +
            (double)(EF[b] + EB[b] - BOOST_BITS * ILv[b]) * 0.6931471805599453;
        per_sample[b] = -(float)lg;
    }
}

__global__ __launch_bounds__(64) void ctc_loss_final(
    const float* __restrict__ per_sample, const int* __restrict__ tl,
    float* __restrict__ out_loss)
{
    int tid = threadIdx.x;
    float v = 0.f;
    if (tid < B_) {
        int t = tl[tid] < 1 ? 1 : tl[tid];
        v = per_sample[tid] / (float)t;
    }
#pragma unroll
    for (int off = 32; off; off >>= 1) v += __shfl_down(v, off);
    if (tid == 0) {
        float loss = v / (float)B_;
        if (isnan(loss) || isinf(loss)) loss = 0.f;
        *out_loss = loss;
    }
}

// ---------------------------------------------------------------------------
extern "C" void kernel_launch(void* const* d_in, const int* in_sizes, int n_in,
                              void* d_out, int out_size, void* d_ws, size_t ws_size,
                              hipStream_t stream)
{
    (void)in_sizes; (void)n_in; (void)out_size; (void)ws_size;

    const float* rep      = (const float*)d_in[0];
    const int*   enc_mask = (const int*)d_in[1];
    const int*   targets  = (const int*)d_in[2];
    const int*   tgt_mask = (const int*)d_in[3];
    const float* W_exp    = (const float*)d_in[4];
    const float* b_exp    = (const float*)d_in[5];
    const float* W1       = (const float*)d_in[6];
    const float* b1       = (const float*)d_in[7];
    const float* W2       = (const float*)d_in[8];
    const float* b2       = (const float*)d_in[9];

    float* out       = (float*)d_out;
    float* logprobs  = out;                          // [65536][512] f32
    float* out_len_f = out + (size_t)B_ * T_ * V_;
    float* out_loss  = out_len_f + B_;
    unsigned short* Hd = (unsigned short*)d_out;     // H bf16 [65536][1024] (same bytes)

    // ws layout (~39.1 MB, within the 39.2 proven):
    unsigned short* WcT = (unsigned short*)d_ws;                  // [4096][512] bf16, 4 MB
    float* bc           = (float*)(WcT + (size_t)4096 * 512);     // [4096]
    float* per_sample   = bc + 4096;                              // [64]
    int*   tl_out       = (int*)(per_sample + 64);                // [64]
    unsigned short* P   = (unsigned short*)(tl_out + 64);         // [65536][264], 34.6 MB
    double* AV          = (double*)(P + (size_t)65536 * PSTRIDE); // [32][520] f64
    double* BV          = AV + 32 * 520;                          // [32][520] f64
    int*   EF           = (int*)(BV + 32 * 520);                  // [32]
    int*   EB           = EF + 32;                                // [32]
    int*   ILv          = EB + 32;                                // [32]
    // aliased inside P (all dead before gather_p writes P):
    unsigned short* repb   = P;                                   // [16384][512]
    unsigned short* W_expb = P + (size_t)16384 * 512;             // [512][2048]
    unsigned short* W1T    = W_expb + (size_t)512 * 2048;         // [1024][512]
    unsigned short* W2T    = WcT;                                 // [512][1024] (after gemm1)

    // 1) conversions
    cvt_f32_bf16<<<8192, 256, 0, stream>>>(rep, repb, (16384 * 512) / 4);
    cvt_f32_bf16<<<1024, 256, 0, stream>>>(W_exp, W_expb, (512 * 2048) / 4);
    transpose_cvt<<<dim3(32, 16), dim3(32, 8), 0, stream>>>(W1, W1T, 512, 1024);

    // 2) fold via MFMA: WcT[(k*1024+h)][e] = sum_d W1T[h][d] * W_exp[e][k*512+d]
    gemm_mfma<false, true, false><<<dim3(4, 8, 4), 256, 0, stream>>>(
        W1T, 512, 0, W_expb, 2048, 512, WcT, 512, (long)1024 * 512, nullptr, 512);
    combine_bias<<<16, 256, 0, stream>>>(b_exp, W1, b1, bc);

    // 3) GEMM1 (single launch): H = relu(rep @ Wc + bc) bf16 -> d_out
    gemm_mfma<true, true, true><<<dim3(32, 128), 256, 0, stream>>>(
        repb, 512, 0, WcT, 512, 0, Hd, 4096, 0, bc, 512);

    // 4) W2 -> W2T (into the now-dead WcT region)
    transpose_cvt<<<dim3(16, 32), dim3(32, 8), 0, stream>>>(W2, W2T, 1024, 512);

    // 5) fused GEMM2 + log_softmax (in-place lp over H), then streaming gather
    gemm2_lsm<<<2048, 256, 0, stream>>>(Hd, W2T, b2, logprobs);
    gather_p<<<(B_ * T_) / 4, 256, 0, stream>>>(logprobs, targets, P);

    // 6) CTC DP: fwd (blocks 0-31) + bwd (blocks 32-63), combine, loss
    ctc_fwd_bwd<<<64, 64, 0, stream>>>(P, enc_mask, targets, tgt_mask,
                                       out_len_f, AV, BV, EF, EB, ILv, tl_out);
    ctc_combine<<<32, 64, 0, stream>>>(AV, BV, EF, EB, ILv, per_sample);
    ctc_loss_final<<<1, 64, 0, stream>>>(per_sample, tl_out, out_loss);
}

// Round 12
// 421.201 us; speedup vs baseline: 1.4825x; 1.3306x over previous
//
#include <hip/hip_runtime.h>
#include <math.h>

#define B_ 32
#define SSRC 512
#define D_ 512
#define STRIDE_ 4
#define V_ 512
#define L_ 256
#define T_ (SSRC * STRIDE_)   // 2048
#define S_ (2 * L_ + 1)       // 513
#define BLANKI 1
#define PSTRIDE 264           // compact prob row stride (ushorts)
#define BOOST 4096.0f         // 2^12 pre-boost on gathered probs
#define BOOST_BITS 12

typedef __attribute__((ext_vector_type(8))) short bf16x8;
typedef __attribute__((ext_vector_type(4))) float f32x4;

__device__ __forceinline__ unsigned short bf16r(float x) {
    unsigned u = __float_as_uint(x);
    return (unsigned short)((u + 0x7fffu + ((u >> 16) & 1u)) >> 16);
}
__device__ __forceinline__ float bf2f(unsigned short u) {
    return __uint_as_float((unsigned)u << 16);
}
__device__ __forceinline__ void gl_lds16(const unsigned short* g, unsigned short* l) {
    __builtin_amdgcn_global_load_lds(
        (const __attribute__((address_space(1))) unsigned int*)g,
        (__attribute__((address_space(3))) unsigned int*)l, 16, 0, 0);
}

// ---------------------------------------------------------------------------
__global__ __launch_bounds__(256) void combine_bias(
    const float* __restrict__ b_exp, const float* __restrict__ W1,
    const float* __restrict__ b1, float* __restrict__ bc)
{
    int j = blockIdx.x * 256 + threadIdx.x;
    int k = j >> 10, h = j & 1023;
    float s = b1[h];
    const float* be = b_exp + k * 512;
    for (int d = 0; d < 512; ++d)
        s = fmaf(be[d], W1[d * 1024 + h], s);
    bc[j] = s;
}

// ---------------------------------------------------------------------------
__global__ __launch_bounds__(256) void transpose_cvt(
    const float* __restrict__ in, unsigned short* __restrict__ out, int R, int C)
{
    __shared__ float tile[32][33];
    int bx = blockIdx.x * 32, by = blockIdx.y * 32;
    int tx = threadIdx.x, ty = threadIdx.y;
#pragma unroll
    for (int i = 0; i < 32; i += 8)
        tile[ty + i][tx] = in[(size_t)(by + ty + i) * C + bx + tx];
    __syncthreads();
#pragma unroll
    for (int i = 0; i < 32; i += 8)
        out[(size_t)(bx + ty + i) * R + by + tx] = bf16r(tile[tx][ty + i]);
}

__global__ __launch_bounds__(256) void cvt_f32_bf16(
    const float* __restrict__ in, unsigned short* __restrict__ out, int n4)
{
    int i = blockIdx.x * 256 + threadIdx.x;
    if (i >= n4) return;
    float4 v = ((const float4*)in)[i];
    ushort4 o;
    o.x = bf16r(v.x); o.y = bf16r(v.y); o.z = bf16r(v.z); o.w = bf16r(v.w);
    ((ushort4*)out)[i] = o;
}

// ---------------------------------------------------------------------------
// bf16 MFMA GEMM (m97 structure) + bijective XCD swizzle (nwg % 8 == 0).
// Optional gridDim.z slicing via element offsets zA/zBT/zC.
// ---------------------------------------------------------------------------
template <bool RELU, bool OUTBF16, bool BIAS>
__global__ __launch_bounds__(256) void gemm_mfma(
    const unsigned short* __restrict__ A, int lda, long zA,
    const unsigned short* __restrict__ BT, int ldb, long zBT,
    void* __restrict__ Cvoid, int ldc, long zC,
    const float* __restrict__ bias, int K)
{
    __shared__ unsigned short As[2][128][32];
    __shared__ unsigned short Bs[2][128][32];
    const int tid = threadIdx.x;
    const int wid = tid >> 6, lane = tid & 63;

    A  += (size_t)blockIdx.z * zA;
    BT += (size_t)blockIdx.z * zBT;
    unsigned short* Cb = OUTBF16 ? ((unsigned short*)Cvoid + (size_t)blockIdx.z * zC) : nullptr;
    float*          Cf = OUTBF16 ? nullptr : ((float*)Cvoid + (size_t)blockIdx.z * zC);

    const int gx = gridDim.x;
    int wg = blockIdx.y * gx + blockIdx.x;
    const int q = (gx * gridDim.y) >> 3;
    wg = (wg & 7) * q + (wg >> 3);
    const int bm = (wg / gx) * 128, bn = (wg % gx) * 128;

    const int wm = (wid >> 1) * 64, wn = (wid & 1) * 64;

    f32x4 acc[4][4] = {};
    const int r_in = lane >> 2;
    const int cch = (lane & 3) * 8;
    const int rbase = wid * 32;

    auto stage = [&](int buf, int k0) {
#pragma unroll
        for (int i = 0; i < 2; ++i) {
            int rloc = rbase + i * 16;
            gl_lds16(A  + (size_t)(bm + rloc + r_in) * lda + k0 + cch, &As[buf][rloc][0]);
            gl_lds16(BT + (size_t)(bn + rloc + r_in) * ldb + k0 + cch, &Bs[buf][rloc][0]);
        }
    };

    const int nt = K / 32;
    stage(0, 0);
    for (int t = 0; t < nt; ++t) {
        int cur = t & 1;
        __syncthreads();
        if (t + 1 < nt) stage(cur ^ 1, (t + 1) * 32);
        bf16x8 af[4], bfr[4];
#pragma unroll
        for (int mi = 0; mi < 4; ++mi)
            af[mi] = *(const bf16x8*)&As[cur][wm + mi * 16 + (lane & 15)][(lane >> 4) * 8];
#pragma unroll
        for (int ni = 0; ni < 4; ++ni)
            bfr[ni] = *(const bf16x8*)&Bs[cur][wn + ni * 16 + (lane & 15)][(lane >> 4) * 8];
#pragma unroll
        for (int mi = 0; mi < 4; ++mi)
#pragma unroll
            for (int ni = 0; ni < 4; ++ni)
                acc[mi][ni] = __builtin_amdgcn_mfma_f32_16x16x32_bf16(
                    af[mi], bfr[ni], acc[mi][ni], 0, 0, 0);
    }

#pragma unroll
    for (int ni = 0; ni < 4; ++ni) {
        int gcol = bn + wn + ni * 16 + (lane & 15);
        float bv = BIAS ? bias[gcol] : 0.f;
#pragma unroll
        for (int mi = 0; mi < 4; ++mi) {
#pragma unroll
            for (int q2 = 0; q2 < 4; ++q2) {
                int grow = bm + wm + mi * 16 + ((lane >> 4) << 2) + q2;
                float x = acc[mi][ni][q2] + bv;
                if (RELU) x = fmaxf(x, 0.f);
                if (OUTBF16)
                    Cb[(size_t)grow * ldc + gcol] = bf16r(x);
                else
                    Cf[(size_t)grow * ldc + gcol] = x;
            }
        }
    }
}

// ---------------------------------------------------------------------------
// Fused GEMM2 + log_softmax, v3: m97-style LDS staging for BOTH operands.
// One block = 128 logits rows x V=512 (full rows => block-local softmax,
// in-place lp over H is race-free). 8 waves = 2 row-groups x 4 col-groups;
// each wave computes 64x128 via acc[4][8], 32 MFMA per k-step between
// barriers (R11 version loaded B from global per step: L2 latency exposed,
// MfmaUtil 10.8%, 259us).
// LDS 80KB static: As[2][128][32] + Bs[2][512][32]; reductions alias As
// after the K-loop.
// ---------------------------------------------------------------------------
__global__ __launch_bounds__(512) void gemm2_lsm(
    const unsigned short* __restrict__ H,     // [65536][1024] bf16 (= d_out)
    const unsigned short* __restrict__ W2T,   // [512][1024] bf16
    const float* __restrict__ b2,             // [512]
    float* __restrict__ lp)                   // [65536][512] f32 (= d_out)
{
    __shared__ __align__(16) char SMEM[81920];
    unsigned short* As = (unsigned short*)SMEM;            // [2][128][32]
    unsigned short* Bs = (unsigned short*)(SMEM + 16384);  // [2][512][32]
    float* redm = (float*)SMEM;                            // [4][128] (post-loop)
    float* reds = (float*)(SMEM + 2048);                   // [4][128]

    const int tid = threadIdx.x;
    const int wid = tid >> 6, lane = tid & 63;
    const int wr = wid >> 2, wc = wid & 3;     // row-group 0..1, col-group 0..3
    const int r0 = blockIdx.x * 128;

    // staging per k-step: 8 A-issues (128 rows) + 32 B-issues (512 rows) = 40;
    // 5 per wave; each issue = 16 rows x 32k (1KB), wave-uniform LDS base.
    auto stage = [&](int buf, int k0) {
#pragma unroll
        for (int ii = 0; ii < 5; ++ii) {
            int issue = wid * 5 + ii;
            if (issue < 8) {
                int rr = issue * 16;
                gl_lds16(H + (size_t)(r0 + rr + (lane >> 2)) * 1024 + k0 + (lane & 3) * 8,
                         &As[buf * 4096 + rr * 32]);
            } else {
                int rr = (issue - 8) * 16;
                gl_lds16(W2T + (size_t)(rr + (lane >> 2)) * 1024 + k0 + (lane & 3) * 8,
                         &Bs[buf * 16384 + rr * 32]);
            }
        }
    };

    f32x4 acc[4][8] = {};
    stage(0, 0);
    for (int t = 0; t < 32; ++t) {
        const int cur = t & 1;
        __syncthreads();
        if (t + 1 < 32) stage(cur ^ 1, (t + 1) * 32);
        bf16x8 af[4], bfr[8];
#pragma unroll
        for (int mi = 0; mi < 4; ++mi)
            af[mi] = *(const bf16x8*)&As[cur * 4096 +
                        (wr * 64 + mi * 16 + (lane & 15)) * 32 + (lane >> 4) * 8];
#pragma unroll
        for (int ni = 0; ni < 8; ++ni)
            bfr[ni] = *(const bf16x8*)&Bs[cur * 16384 +
                        (wc * 128 + ni * 16 + (lane & 15)) * 32 + (lane >> 4) * 8];
#pragma unroll
        for (int mi = 0; mi < 4; ++mi)
#pragma unroll
            for (int ni = 0; ni < 8; ++ni)
                acc[mi][ni] = __builtin_amdgcn_mfma_f32_16x16x32_bf16(
                    af[mi], bfr[ni], acc[mi][ni], 0, 0, 0);
    }

    // ---- epilogue: bias + block-local row softmax + in-place lp write ----
    float bcol[8];
#pragma unroll
    for (int ni = 0; ni < 8; ++ni) bcol[ni] = b2[wc * 128 + ni * 16 + (lane & 15)];
#pragma unroll
    for (int mi = 0; mi < 4; ++mi)
#pragma unroll
        for (int ni = 0; ni < 8; ++ni)
#pragma unroll
            for (int q = 0; q < 4; ++q) acc[mi][ni][q] += bcol[ni];

    __syncthreads();   // LDS reuse: staging dead, reductions alias As

    float rm[4][4];
#pragma unroll
    for (int mi = 0; mi < 4; ++mi)
#pragma unroll
        for (int q = 0; q < 4; ++q) {
            float m = acc[mi][0][q];
#pragma unroll
            for (int ni = 1; ni < 8; ++ni) m = fmaxf(m, acc[mi][ni][q]);
#pragma unroll
            for (int off = 1; off < 16; off <<= 1) m = fmaxf(m, __shfl_xor(m, off));
            rm[mi][q] = m;
        }
    if ((lane & 15) == 0) {
#pragma unroll
        for (int mi = 0; mi < 4; ++mi)
#pragma unroll
            for (int q = 0; q < 4; ++q)
                redm[wc * 128 + wr * 64 + mi * 16 + ((lane >> 4) << 2) + q] = rm[mi][q];
    }
    __syncthreads();
#pragma unroll
    for (int mi = 0; mi < 4; ++mi)
#pragma unroll
        for (int q = 0; q < 4; ++q) {
            int row = wr * 64 + mi * 16 + ((lane >> 4) << 2) + q;
            rm[mi][q] = fmaxf(fmaxf(redm[0 * 128 + row], redm[1 * 128 + row]),
                              fmaxf(redm[2 * 128 + row], redm[3 * 128 + row]));
        }
    float rs[4][4];
#pragma unroll
    for (int mi = 0; mi < 4; ++mi)
#pragma unroll
        for (int q = 0; q < 4; ++q) {
            float s = 0.f;
#pragma unroll
            for (int ni = 0; ni < 8; ++ni) s += expf(acc[mi][ni][q] - rm[mi][q]);
#pragma unroll
            for (int off = 1; off < 16; off <<= 1) s += __shfl_xor(s, off);
            rs[mi][q] = s;
        }
    if ((lane & 15) == 0) {
#pragma unroll
        for (int mi = 0; mi < 4; ++mi)
#pragma unroll
            for (int q = 0; q < 4; ++q)
                reds[wc * 128 + wr * 64 + mi * 16 + ((lane >> 4) << 2) + q] = rs[mi][q];
    }
    __syncthreads();
#pragma unroll
    for (int mi = 0; mi < 4; ++mi)
#pragma unroll
        for (int q = 0; q < 4; ++q) {
            int row = wr * 64 + mi * 16 + ((lane >> 4) << 2) + q;
            float st = (reds[0 * 128 + row] + reds[1 * 128 + row]) +
                       (reds[2 * 128 + row] + reds[3 * 128 + row]);
            float lse = rm[mi][q] + logf(st);
#pragma unroll
            for (int ni = 0; ni < 8; ++ni) {
                int col = wc * 128 + ni * 16 + (lane & 15);
                lp[(size_t)(r0 + row) * 512 + col] = acc[mi][ni][q] - lse;
            }
        }
}

// ---------------------------------------------------------------------------
// Streaming gather: P[w][j] = bf16(exp(lp[w][tg_j])*BOOST), P[w][256] = blank.
// ---------------------------------------------------------------------------
__global__ __launch_bounds__(256) void gather_p(
    const float* __restrict__ lp, const int* __restrict__ targets,
    unsigned short* __restrict__ P)
{
    const int w = (blockIdx.x << 2) + (threadIdx.x >> 6);
    const int l = threadIdx.x & 63;
    const int wl = threadIdx.x >> 6;
    const int b = w >> 11;

    __shared__ unsigned short pr[4][512];
    const float* row = lp + (size_t)w * 512;
    float4 v0 = ((const float4*)row)[l];
    float4 v1 = ((const float4*)row)[64 + l];
    pr[wl][l * 4 + 0] = bf16r(expf(v0.x) * BOOST);
    pr[wl][l * 4 + 1] = bf16r(expf(v0.y) * BOOST);
    pr[wl][l * 4 + 2] = bf16r(expf(v0.z) * BOOST);
    pr[wl][l * 4 + 3] = bf16r(expf(v0.w) * BOOST);
    pr[wl][256 + l * 4 + 0] = bf16r(expf(v1.x) * BOOST);
    pr[wl][256 + l * 4 + 1] = bf16r(expf(v1.y) * BOOST);
    pr[wl][256 + l * 4 + 2] = bf16r(expf(v1.z) * BOOST);
    pr[wl][256 + l * 4 + 3] = bf16r(expf(v1.w) * BOOST);
    __syncthreads();

    int4 tg = ((const int4*)(targets + (size_t)b * L_))[l];
    ushort4 o;
    o.x = pr[wl][tg.x]; o.y = pr[wl][tg.y]; o.z = pr[wl][tg.z]; o.w = pr[wl][tg.w];
    *(ushort4*)&P[(size_t)w * PSTRIDE + l * 4] = o;
    if (l == 0) P[(size_t)w * PSTRIDE + 256] = pr[wl][BLANKI];
}

// ---------------------------------------------------------------------------
// CTC forward/backward DP split, f64, depth-16 NAMED-register pipeline
// (R9 structure, measured 148.8us). Rescale once per 16 steps.
// ---------------------------------------------------------------------------
struct Pr5 { float pb, p1, p3, p5, p7; };

__device__ __forceinline__ Pr5 ldrowf(const unsigned short* rp, int l)
{
    ushort4 q = *(const ushort4*)(rp + 4 * l);
    Pr5 r;
    r.pb = bf2f(rp[256]);
    r.p1 = bf2f(q.x); r.p3 = bf2f(q.y); r.p5 = bf2f(q.z); r.p7 = bf2f(q.w);
    return r;
}

#define REP16(OP) OP(0) OP(1) OP(2) OP(3) OP(4) OP(5) OP(6) OP(7) \
                  OP(8) OP(9) OP(10) OP(11) OP(12) OP(13) OP(14) OP(15)

__global__ __launch_bounds__(64) void ctc_fwd_bwd(
    const unsigned short* __restrict__ P,
    const int* __restrict__ enc_mask, const int* __restrict__ targets,
    const int* __restrict__ tgt_mask,
    float* __restrict__ out_len_f,
    double* __restrict__ AV, double* __restrict__ BV,
    int* __restrict__ EF, int* __restrict__ EB,
    int* __restrict__ ILv, int* __restrict__ tl_out)
{
    const int b = blockIdx.x & 31;
    const bool isf = blockIdx.x < 32;
    const int l = threadIdx.x;

    int se = 0, st = 0;
    {
        const int* em = enc_mask + (size_t)b * SSRC;
#pragma unroll
        for (int i = 0; i < 8; ++i) se += (em[i * 64 + l] != 0) ? 1 : 0;
        const int* tm = tgt_mask + (size_t)b * L_;
#pragma unroll
        for (int i = 0; i < 4; ++i) st += (tm[i * 64 + l] != 0) ? 1 : 0;
#pragma unroll
        for (int off = 32; off; off >>= 1) {
            se += __shfl_xor(se, off);
            st += __shfl_xor(st, off);
        }
    }
    const int tl = st;
    const int IL = STRIDE_ * se;
    const int h = (IL > 0) ? ((IL - 1) >> 1) : 0;

    const int4 tg = ((const int4*)(targets + (size_t)b * L_))[l];
    int prevw = __shfl_up(tg.w, 1);
    if (l == 0) prevw = BLANKI;
    const bool k1 = (tg.x != BLANKI) && (tg.x != prevw);
    const bool k3 = (tg.y != BLANKI) && (tg.y != tg.x);
    const bool k5 = (tg.z != BLANKI) && (tg.z != tg.y);
    const bool k7 = (tg.w != BLANKI) && (tg.w != tg.z);

    const unsigned short* Pb = P + (size_t)b * T_ * PSTRIDE;

    double a0 = 0, a1 = 0, a2 = 0, a3 = 0, a4 = 0, a5 = 0, a6 = 0, a7 = 0, a8 = 0;
    int Ei = 0;

    auto rescale9 = [&]() {
        double m = fmax(fmax(fmax(a0, a1), fmax(a2, a3)),
                        fmax(fmax(a4, a5), fmax(fmax(a6, a7), a8)));
        int e = (int)((__double_as_longlong(m) >> 52) & 0x7ff);
#pragma unroll
        for (int off = 1; off < 64; off <<= 1) {
            int o = __shfl_xor(e, off);
            e = o > e ? o : e;
        }
        int sh = 1023 - e;
        double sc = __longlong_as_double(((long long)(sh + 1023)) << 52);
        Ei += e - 1023;
        a0 *= sc; a1 *= sc; a2 *= sc; a3 *= sc; a4 *= sc;
        a5 *= sc; a6 *= sc; a7 *= sc; a8 *= sc;
    };

    if (isf) {
        if (l == 0) {
            a0 = (double)bf2f(Pb[256]);
            if (tl > 0) a1 = (double)bf2f(Pb[0]);
        }
        auto fstep = [&](const Pr5& r) {
            double pb = (double)r.pb, p1 = (double)r.p1, p3 = (double)r.p3;
            double p5 = (double)r.p5, p7 = (double)r.p7;
            double u1 = __shfl_up(a7, 1);
            if (l == 0) u1 = 0.0;
            double n0 = (a0 + u1) * pb;
            double n1 = (a0 + a1 + (k1 ? u1 : 0.0)) * p1;
            double n2 = (a1 + a2) * pb;
            double n3 = (a2 + a3 + (k3 ? a1 : 0.0)) * p3;
            double n4 = (a3 + a4) * pb;
            double n5 = (a4 + a5 + (k5 ? a3 : 0.0)) * p5;
            double n6 = (a5 + a6) * pb;
            double n7 = (a6 + a7 + (k7 ? a5 : 0.0)) * p7;
            double n8 = (l == 63) ? (a7 + a8) * pb : 0.0;
            a0 = n0; a1 = n1; a2 = n2; a3 = n3; a4 = n4;
            a5 = n5; a6 = n6; a7 = n7; a8 = n8;
        };
        const int nst = h;
        if (nst > 0) {
            Pr5 q0, q1, q2, q3, q4, q5, q6, q7, q8, q9, q10, q11, q12, q13, q14, q15;
#define LDI(i) { int ti = 1 + i; if (ti > nst) ti = nst; \
                 q##i = ldrowf(Pb + (size_t)ti * PSTRIDE, l); }
            REP16(LDI)
#undef LDI
            int t = 1;
            while (t + 15 <= nst) {
#define STP(i) { fstep(q##i); int ti = t + 16 + i; if (ti > nst) ti = nst; \
                 q##i = ldrowf(Pb + (size_t)ti * PSTRIDE, l); }
                REP16(STP)
#undef STP
                rescale9();
                t += 16;
            }
            int rem = nst - t + 1;
#define TLS(i) if (i < rem) fstep(q##i);
            REP16(TLS)
#undef TLS
        }
        rescale9();
        double* av = AV + b * 520;
        av[l * 8 + 0] = a0; av[l * 8 + 1] = a1; av[l * 8 + 2] = a2; av[l * 8 + 3] = a3;
        av[l * 8 + 4] = a4; av[l * 8 + 5] = a5; av[l * 8 + 6] = a6; av[l * 8 + 7] = a7;
        if (l == 63) av[512] = a8;
        if (l == 0) {
            EF[b] = Ei; ILv[b] = IL; tl_out[b] = tl;
            out_len_f[b] = (float)IL;
        }
    } else {
        {
            int s0 = l * 8;
            int e0 = 2 * tl, e1 = 2 * tl - 1;
            a0 = (s0 + 0 == e0 || (tl > 0 && s0 + 0 == e1)) ? 1.0 : 0.0;
            a1 = (s0 + 1 == e0 || (tl > 0 && s0 + 1 == e1)) ? 1.0 : 0.0;
            a2 = (s0 + 2 == e0 || (tl > 0 && s0 + 2 == e1)) ? 1.0 : 0.0;
            a3 = (s0 + 3 == e0 || (tl > 0 && s0 + 3 == e1)) ? 1.0 : 0.0;
            a4 = (s0 + 4 == e0 || (tl > 0 && s0 + 4 == e1)) ? 1.0 : 0.0;
            a5 = (s0 + 5 == e0 || (tl > 0 && s0 + 5 == e1)) ? 1.0 : 0.0;
            a6 = (s0 + 6 == e0 || (tl > 0 && s0 + 6 == e1)) ? 1.0 : 0.0;
            a7 = (s0 + 7 == e0 || (tl > 0 && s0 + 7 == e1)) ? 1.0 : 0.0;
            if (l == 63) a8 = (512 == e0) ? 1.0 : 0.0;
        }
        float knff = __shfl_down(k1 ? 1.f : 0.f, 1);
        if (l == 63) knff = 0.f;
        const double knf = (double)knff;
        auto bstep = [&](const Pr5& r) {
            double pb = (double)r.pb, p1 = (double)r.p1, p3 = (double)r.p3;
            double p5 = (double)r.p5, p7 = (double)r.p7;
            double g0 = a0 * pb, g1 = a1 * p1, g2 = a2 * pb, g3 = a3 * p3;
            double g4 = a4 * pb, g5 = a5 * p5, g6 = a6 * pb, g7 = a7 * p7;
            double g8 = (l == 63) ? a8 * pb : 0.0;
            double d1 = __shfl_down(g0, 1);
            double d2 = __shfl_down(g1, 1);
            if (l == 63) { d1 = g8; d2 = 0.0; }
            double m0 = g0 + g1;
            double m1 = g1 + g2 + (k3 ? g3 : 0.0);
            double m2 = g2 + g3;
            double m3 = g3 + g4 + (k5 ? g5 : 0.0);
            double m4 = g4 + g5;
            double m5 = g5 + g6 + (k7 ? g7 : 0.0);
            double m6 = g6 + g7;
            double m7 = g7 + d1 + knf * d2;
            double m8 = (l == 63) ? g8 : 0.0;
            a0 = m0; a1 = m1; a2 = m2; a3 = m3; a4 = m4;
            a5 = m5; a6 = m6; a7 = m7; a8 = m8;
        };
        const int nbs = IL - 1 - h;
        if (nbs > 0) {
            const int rmin = h + 1;
            Pr5 q0, q1, q2, q3, q4, q5, q6, q7, q8, q9, q10, q11, q12, q13, q14, q15;
#define LDB(i) { int ri = IL - 1 - i; if (ri < rmin) ri = rmin; \
                 q##i = ldrowf(Pb + (size_t)ri * PSTRIDE, l); }
            REP16(LDB)
#undef LDB
            int j = 0;
            while (j + 16 <= nbs) {
#define STB(i) { bstep(q##i); int ri = IL - 1 - (j + 16 + i); if (ri < rmin) ri = rmin; \
                 q##i = ldrowf(Pb + (size_t)ri * PSTRIDE, l); }
                REP16(STB)
#undef STB
                rescale9();
                j += 16;
            }
            int rem = nbs - j;
#define TLB(i) if (i < rem) bstep(q##i);
            REP16(TLB)
#undef TLB
        }
        rescale9();
        double* bv = BV + b * 520;
        bv[l * 8 + 0] = a0; bv[l * 8 + 1] = a1; bv[l * 8 + 2] = a2; bv[l * 8 + 3] = a3;
        bv[l * 8 + 4] = a4; bv[l * 8 + 5] = a5; bv[l * 8 + 6] = a6; bv[l * 8 + 7] = a7;
        if (l == 63) bv[512] = a8;
        if (l == 0) EB[b] = Ei;
    }
}

// ---------------------------------------------------------------------------
__global__ __launch_bounds__(64) void ctc_combine(
    const double* __restrict__ AV, const double* __restrict__ BV,
    const int* __restrict__ EF, const int* __restrict__ EB,
    const int* __restrict__ ILv, float* __restrict__ per_sample)
{
    const int b = blockIdx.x, l = threadIdx.x;
    const double* av = AV + b * 520;
    const double* bv = BV + b * 520;
    double s = 0.0;
#pragma unroll
    for (int i = 0; i < 8; ++i)
        s += av[l * 8 + i] * bv[l * 8 + i];
    if (l == 63) s += av[512] * bv[512];
#pragma unroll
    for (int off = 1; off < 64; off <<= 1) s += __shfl_xor(s, off);
    if (l == 0) {
        double lg = log(s) +
            (double)(EF[b] + EB[b] - BOOST_BITS * ILv[b]) * 0.6931471805599453;
        per_sample[b] = -(float)lg;
    }
}

__global__ __launch_bounds__(64) void ctc_loss_final(
    const float* __restrict__ per_sample, const int* __restrict__ tl,
    float* __restrict__ out_loss)
{
    int tid = threadIdx.x;
    float v = 0.f;
    if (tid < B_) {
        int t = tl[tid] < 1 ? 1 : tl[tid];
        v = per_sample[tid] / (float)t;
    }
#pragma unroll
    for (int off = 32; off; off >>= 1) v += __shfl_down(v, off);
    if (tid == 0) {
        float loss = v / (float)B_;
        if (isnan(loss) || isinf(loss)) loss = 0.f;
        *out_loss = loss;
    }
}

// ---------------------------------------------------------------------------
extern "C" void kernel_launch(void* const* d_in, const int* in_sizes, int n_in,
                              void* d_out, int out_size, void* d_ws, size_t ws_size,
                              hipStream_t stream)
{
    (void)in_sizes; (void)n_in; (void)out_size; (void)ws_size;

    const float* rep      = (const float*)d_in[0];
    const int*   enc_mask = (const int*)d_in[1];
    const int*   targets  = (const int*)d_in[2];
    const int*   tgt_mask = (const int*)d_in[3];
    const float* W_exp    = (const float*)d_in[4];
    const float* b_exp    = (const float*)d_in[5];
    const float* W1       = (const float*)d_in[6];
    const float* b1       = (const float*)d_in[7];
    const float* W2       = (const float*)d_in[8];
    const float* b2       = (const float*)d_in[9];

    float* out       = (float*)d_out;
    float* logprobs  = out;                          // [65536][512] f32
    float* out_len_f = out + (size_t)B_ * T_ * V_;
    float* out_loss  = out_len_f + B_;
    unsigned short* Hd = (unsigned short*)d_out;     // H bf16 [65536][1024] (same bytes)

    // ws layout (~39.1 MB, within the 39.2 proven):
    unsigned short* WcT = (unsigned short*)d_ws;                  // [4096][512] bf16, 4 MB
    float* bc           = (float*)(WcT + (size_t)4096 * 512);     // [4096]
    float* per_sample   = bc + 4096;                              // [64]
    int*   tl_out       = (int*)(per_sample + 64);                // [64]
    unsigned short* P   = (unsigned short*)(tl_out + 64);         // [65536][264], 34.6 MB
    double* AV          = (double*)(P + (size_t)65536 * PSTRIDE); // [32][520] f64
    double* BV          = AV + 32 * 520;                          // [32][520] f64
    int*   EF           = (int*)(BV + 32 * 520);                  // [32]
    int*   EB           = EF + 32;                                // [32]
    int*   ILv          = EB + 32;                                // [32]
    // aliased inside P (all dead before gather_p writes P):
    unsigned short* repb   = P;                                   // [16384][512]
    unsigned short* W_expb = P + (size_t)16384 * 512;             // [512][2048]
    unsigned short* W1T    = W_expb + (size_t)512 * 2048;         // [1024][512]
    unsigned short* W2T    = WcT;                                 // [512][1024] (after gemm1)

    // 1) conversions
    cvt_f32_bf16<<<8192, 256, 0, stream>>>(rep, repb, (16384 * 512) / 4);
    cvt_f32_bf16<<<1024, 256, 0, stream>>>(W_exp, W_expb, (512 * 2048) / 4);
    transpose_cvt<<<dim3(32, 16), dim3(32, 8), 0, stream>>>(W1, W1T, 512, 1024);

    // 2) fold via MFMA: WcT[(k*1024+h)][e] = sum_d W1T[h][d] * W_exp[e][k*512+d]
    gemm_mfma<false, true, false><<<dim3(4, 8, 4), 256, 0, stream>>>(
        W1T, 512, 0, W_expb, 2048, 512, WcT, 512, (long)1024 * 512, nullptr, 512);
    combine_bias<<<16, 256, 0, stream>>>(b_exp, W1, b1, bc);

    // 3) GEMM1 (single launch): H = relu(rep @ Wc + bc) bf16 -> d_out
    gemm_mfma<true, true, true><<<dim3(32, 128), 256, 0, stream>>>(
        repb, 512, 0, WcT, 512, 0, Hd, 4096, 0, bc, 512);

    // 4) W2 -> W2T (into the now-dead WcT region)
    transpose_cvt<<<dim3(16, 32), dim3(32, 8), 0, stream>>>(W2, W2T, 1024, 512);

    // 5) fused GEMM2 + log_softmax (in-place lp over H), then streaming gather
    gemm2_lsm<<<512, 512, 0, stream>>>(Hd, W2T, b2, logprobs);
    gather_p<<<(B_ * T_) / 4, 256, 0, stream>>>(logprobs, targets, P);

    // 6) CTC DP: fwd (blocks 0-31) + bwd (blocks 32-63), combine, loss
    ctc_fwd_bwd<<<64, 64, 0, stream>>>(P, enc_mask, targets, tgt_mask,
                                       out_len_f, AV, BV, EF, EB, ILv, tl_out);
    ctc_combine<<<32, 64, 0, stream>>>(AV, BV, EF, EB, ILv, per_sample);
    ctc_loss_final<<<1, 64, 0, stream>>>(per_sample, tl_out, out_loss);
}